// Round 1
// baseline (623.602 us; speedup 1.0000x reference)
//
#include <hip/hip_runtime.h>
#include <hip/hip_bf16.h>

// EAConv: EM-routing neighbor aggregation + temporal blend.
// Shapes fixed by setup_inputs(): T=3, b=1, n=50000, d=64, m=16, K=4, dd=16.
// One 64-lane wave per (t, node); lane j owns element j of the d=64 vector.
// Factor k = j>>4 (4 factors x 16 dims). All norm/dot reductions are
// 16-lane shuffle trees (xor 1,2,4,8); the softmax over K uses xor 16,32.

constexpr int T  = 3;
constexpr int N  = 50000;
constexpr int D  = 64;
constexpr int M  = 16;

__device__ __forceinline__ float group16_sum(float v) {
    v += __shfl_xor(v, 1, 64);
    v += __shfl_xor(v, 2, 64);
    v += __shfl_xor(v, 4, 64);
    v += __shfl_xor(v, 8, 64);
    return v;
}

__global__ __launch_bounds__(256) void eaconv_agg(
    const float* __restrict__ x_all,   // [T, N, D]
    const int*   __restrict__ nbr_all, // [T, N, M]
    float*       __restrict__ out)     // [T, N, D]  <- u_t (pre-blend)
{
    const int wave = (blockIdx.x * blockDim.x + threadIdx.x) >> 6;
    const int lane = threadIdx.x & 63;
    if (wave >= T * N) return;
    const int t = wave / N;
    const int i = wave - t * N;

    const float* x   = x_all   + (size_t)t * N * D;
    const int*   nbr = nbr_all + ((size_t)t * N + i) * M;

    // ---- own factors, normalized per 16-dim factor ----
    float xv = x[(size_t)i * D + lane];
    float xk = xv / fmaxf(sqrtf(group16_sum(xv * xv)), 1e-12f);

    // ---- neighbor indices: lanes 0..15 load, broadcast via shuffle ----
    int myidx = nbr[lane & 15];

    // ---- gather + normalize neighbor factors ----
    float z[M];
#pragma unroll
    for (int m = 0; m < M; ++m) {
        int j = __shfl(myidx, m, 64);
        float zv = ((unsigned)j < (unsigned)N) ? x[(size_t)j * D + lane] : 0.0f;
        z[m] = zv / fmaxf(sqrtf(group16_sum(zv * zv)), 1e-12f);
    }

    // ---- iteration 0: p = 1/K uniform ----
    float u = 0.0f;
#pragma unroll
    for (int m = 0; m < M; ++m) u += z[m];
    u = 0.25f * u + xk;
    u = u / fmaxf(sqrtf(group16_sum(u * u)), 1e-12f);

    // ---- iterations 1..2 ----
#pragma unroll
    for (int it = 1; it < 3; ++it) {
        float unew = xk;
#pragma unroll
        for (int m = 0; m < M; ++m) {
            // logit[m][k] = <z[m], u> within my factor group
            float prod = group16_sum(z[m] * u);
            // softmax over the 4 factors (lanes xor 16, 32)
            float mx = prod;
            mx = fmaxf(mx, __shfl_xor(mx, 16, 64));
            mx = fmaxf(mx, __shfl_xor(mx, 32, 64));
            float e = __expf(prod - mx);
            float s = e;
            s += __shfl_xor(s, 16, 64);
            s += __shfl_xor(s, 32, 64);
            unew = fmaf(z[m], e / s, unew);
        }
        u = unew;
        if (it < 2)  // no normalize after the last iteration
            u = u / fmaxf(sqrtf(group16_sum(u * u)), 1e-12f);
    }

    out[((size_t)t * N + i) * D + lane] = u;
}

// Temporal blend, closed form (sigmoid(0)=0.5, sigmoid(1)=0.7310585786):
//   e0 = u0
//   e1 = (0.5*e0)/1*0.5 + 0.5*u1
//   e2 = ((0.5*e0 + sig1*e1)/2)*0.5 + 0.5*u2
__global__ __launch_bounds__(256) void eaconv_combine(float* __restrict__ out) {
    const int nd = N * D;
    int idx = blockIdx.x * blockDim.x + threadIdx.x;
    if (idx >= nd) return;
    float u0 = out[idx];
    float u1 = out[nd + idx];
    float u2 = out[2 * nd + idx];
    float e0 = u0;
    float e1 = 0.5f * e0 * 0.5f + 0.5f * u1;
    float e2 = (0.5f * e0 + 0.7310585786300049f * e1) * 0.25f + 0.5f * u2;
    out[nd + idx] = e1;
    out[2 * nd + idx] = e2;
}

extern "C" void kernel_launch(void* const* d_in, const int* in_sizes, int n_in,
                              void* d_out, int out_size, void* d_ws, size_t ws_size,
                              hipStream_t stream) {
    const float* x_all = (const float*)d_in[0];
    const int*   nbrs  = (const int*)d_in[1];
    float*       out   = (float*)d_out;

    // one wave per (t, node): 150000 waves, 4 waves/block -> 37500 blocks
    const int total_threads = T * N * 64;
    eaconv_agg<<<(total_threads + 255) / 256, 256, 0, stream>>>(x_all, nbrs, out);

    const int nd = N * D;
    eaconv_combine<<<(nd + 255) / 256, 256, 0, stream>>>(out);
}